// Round 4
// baseline (584.134 us; speedup 1.0000x reference)
//
#include <hip/hip_runtime.h>
#include <hip/hip_bf16.h>

// 3-layer GCN, CSR gather-reduce formulation (no float atomics).
//   hs = dinv[row] * (act(prev) @ W)          (GEMM, act = BN+ReLU fused)
//   y[i] = dinv[i]*(hs[i] + sum_{e: s->i} hs[s]) + b
// CSR built per call: count degrees -> 3-phase parallel scan ->
// destructive-cursor placement (rowptr[i] becomes end-of-row i).

__global__ void count_deg_kernel(const int* __restrict__ dst, int E,
                                 int* __restrict__ rowptr1 /* rowptr+1 */) {
    int e = blockIdx.x * blockDim.x + threadIdx.x;
    if (e < E) atomicAdd(rowptr1 + dst[e], 1);
}

// dinv[i] = rsqrt(deg_i + 1); deg_i lives at rowptr[i+1] (pre-scan)
__global__ void dinv_kernel(const int* __restrict__ rowptr, int n,
                            float* __restrict__ dinv) {
    int i = blockIdx.x * blockDim.x + threadIdx.x;
    if (i < n) dinv[i] = rsqrtf((float)(rowptr[i + 1] + 1));
}

// ---- 3-phase parallel inclusive scan over rowptr[0..total) ----
__global__ __launch_bounds__(256) void scanA_kernel(int* __restrict__ data,
                                                    int total,
                                                    int* __restrict__ bsum) {
    __shared__ int sh[256];
    const int t = threadIdx.x;
    const int base = blockIdx.x * 2048 + t * 8;
    int v[8];
    int run = 0;
#pragma unroll
    for (int j = 0; j < 8; ++j) {
        int idx = base + j;
        int x = (idx < total) ? data[idx] : 0;
        run += x;
        v[j] = run;
    }
    sh[t] = run;
    __syncthreads();
#pragma unroll
    for (int off = 1; off < 256; off <<= 1) {
        int add = (t >= off) ? sh[t - off] : 0;
        __syncthreads();
        sh[t] += add;
        __syncthreads();
    }
    int prev = (t > 0) ? sh[t - 1] : 0;
#pragma unroll
    for (int j = 0; j < 8; ++j) {
        int idx = base + j;
        if (idx < total) data[idx] = v[j] + prev;
    }
    if (t == 255) bsum[blockIdx.x] = sh[255];
}

__global__ void scanB_kernel(int* __restrict__ bsum, int nb) {
    __shared__ int sh[64];
    const int t = threadIdx.x;
    sh[t] = (t < nb) ? bsum[t] : 0;
    __syncthreads();
#pragma unroll
    for (int off = 1; off < 64; off <<= 1) {
        int add = (t >= off) ? sh[t - off] : 0;
        __syncthreads();
        sh[t] += add;
        __syncthreads();
    }
    if (t < nb) bsum[t] = sh[t];
}

__global__ __launch_bounds__(256) void scanC_kernel(int* __restrict__ data,
                                                    int total,
                                                    const int* __restrict__ bsum) {
    if (blockIdx.x == 0) return;
    const int off = bsum[blockIdx.x - 1];
    const int base = blockIdx.x * 2048 + threadIdx.x * 8;
#pragma unroll
    for (int j = 0; j < 8; ++j) {
        int idx = base + j;
        if (idx < total) data[idx] += off;
    }
}

// destructive cursor: rowptr[d] advances start->end while placing srcs
__global__ void csr_build_kernel(const int* __restrict__ src,
                                 const int* __restrict__ dst, int E,
                                 int* __restrict__ rowptr,
                                 int* __restrict__ csr_src) {
    int e = blockIdx.x * blockDim.x + threadIdx.x;
    if (e < E) {
        int pos = atomicAdd(rowptr + dst[e], 1);
        csr_src[pos] = src[e];
    }
}

// C[n x NC] = dinv[row] * (act(A[n x 128]) * W[128 x NC])
// act = identity or BN(scale,shift)+ReLU. 64x64 tile, 256 thr, 4x4 micro.
template <int NC, bool TRANS>
__global__ __launch_bounds__(256) void gemm_k128(
    const float* __restrict__ A, const float* __restrict__ W,
    float* __restrict__ C, int n, const float* __restrict__ ss,
    const float* __restrict__ dinv) {
    __shared__ float As[32][64];  // [k][row]
    __shared__ float Ws[32][64];  // [k][col]
    const int tid = threadIdx.x;
    const int row0 = blockIdx.x * 64;
    const int col0 = blockIdx.y * 64;
    const int tx = tid & 15, ty = tid >> 4;
    const int ar = tid >> 3;        // 0..31
    const int akq = (tid & 7) * 4;  // k quad
    const int wk = tid >> 4;        // 0..15
    const int wjq = (tid & 15) * 4; // col quad
    float acc[4][4] = {};

    for (int kb = 0; kb < 128; kb += 32) {
#pragma unroll
        for (int half = 0; half < 2; ++half) {
            int row = row0 + ar + half * 32;
            float4 v = make_float4(0.f, 0.f, 0.f, 0.f);
            if (row < n)
                v = *reinterpret_cast<const float4*>(A + (size_t)row * 128 + kb + akq);
            if (TRANS) {
                float4 sc = *reinterpret_cast<const float4*>(ss + kb + akq);
                float4 sh = *reinterpret_cast<const float4*>(ss + 128 + kb + akq);
                v.x = fmaxf(fmaf(v.x, sc.x, sh.x), 0.f);
                v.y = fmaxf(fmaf(v.y, sc.y, sh.y), 0.f);
                v.z = fmaxf(fmaf(v.z, sc.z, sh.z), 0.f);
                v.w = fmaxf(fmaf(v.w, sc.w, sh.w), 0.f);
            }
            As[akq + 0][ar + half * 32] = v.x;
            As[akq + 1][ar + half * 32] = v.y;
            As[akq + 2][ar + half * 32] = v.z;
            As[akq + 3][ar + half * 32] = v.w;
        }
#pragma unroll
        for (int half = 0; half < 2; ++half) {
            int k = kb + wk + half * 16;
            float4 w = *reinterpret_cast<const float4*>(W + (size_t)k * NC + col0 + wjq);
            *reinterpret_cast<float4*>(&Ws[wk + half * 16][wjq]) = w;
        }
        __syncthreads();
#pragma unroll
        for (int kk = 0; kk < 32; ++kk) {
            float4 a4 = *reinterpret_cast<const float4*>(&As[kk][ty * 4]);
            float4 b4 = *reinterpret_cast<const float4*>(&Ws[kk][tx * 4]);
            float av[4] = {a4.x, a4.y, a4.z, a4.w};
            float bv[4] = {b4.x, b4.y, b4.z, b4.w};
#pragma unroll
            for (int r = 0; r < 4; ++r)
#pragma unroll
                for (int c = 0; c < 4; ++c)
                    acc[r][c] = fmaf(av[r], bv[c], acc[r][c]);
        }
        __syncthreads();
    }
#pragma unroll
    for (int r = 0; r < 4; ++r) {
        int row = row0 + ty * 4 + r;
        if (row < n) {
            float di = dinv[row];
            float4 o = make_float4(acc[r][0] * di, acc[r][1] * di,
                                   acc[r][2] * di, acc[r][3] * di);
            *reinterpret_cast<float4*>(C + (size_t)row * NC + col0 + tx * 4) = o;
        }
    }
}

// y[i] = dinv[i]*(hs[i] + sum_{e in row i} hs[csr_src[e]]) + bias
// one LANES-lane group per node, float4 per lane; edge loop unrolled x4 so
// 4 independent 512B gathers are in flight per group. Optional BN stats.
// rowptr is POST-BUILD (rowptr[i] = end of row i; start = rowptr[i-1]).
template <int F, bool STATS>
__global__ __launch_bounds__(256) void aggregate_kernel(
    const float* __restrict__ hs, const int* __restrict__ csr_src,
    const int* __restrict__ rowptr, const float* __restrict__ dinv,
    const float* __restrict__ bias, float* __restrict__ out, int n,
    float* __restrict__ stats) {
    const int LANES = F / 4;
    const int GROUPS = 256 / LANES;
    const int lane = threadIdx.x % LANES;
    const int grp = threadIdx.x / LANES;
    const int fq = lane * 4;
    const float4 b4 = *reinterpret_cast<const float4*>(bias + fq);
    float s[4] = {}, sq[4] = {};

    for (int i = blockIdx.x * GROUPS + grp; i < n; i += gridDim.x * GROUPS) {
        int beg = (i == 0) ? 0 : rowptr[i - 1];
        int end = rowptr[i];
        float4 acc = *reinterpret_cast<const float4*>(hs + (size_t)i * F + fq);
        int e = beg;
        for (; e + 3 < end; e += 4) {
            int s0 = csr_src[e], s1 = csr_src[e + 1];
            int s2 = csr_src[e + 2], s3 = csr_src[e + 3];
            float4 v0 = *reinterpret_cast<const float4*>(hs + (size_t)s0 * F + fq);
            float4 v1 = *reinterpret_cast<const float4*>(hs + (size_t)s1 * F + fq);
            float4 v2 = *reinterpret_cast<const float4*>(hs + (size_t)s2 * F + fq);
            float4 v3 = *reinterpret_cast<const float4*>(hs + (size_t)s3 * F + fq);
            acc.x += (v0.x + v1.x) + (v2.x + v3.x);
            acc.y += (v0.y + v1.y) + (v2.y + v3.y);
            acc.z += (v0.z + v1.z) + (v2.z + v3.z);
            acc.w += (v0.w + v1.w) + (v2.w + v3.w);
        }
        for (; e < end; ++e) {
            int s0 = csr_src[e];
            float4 v0 = *reinterpret_cast<const float4*>(hs + (size_t)s0 * F + fq);
            acc.x += v0.x;
            acc.y += v0.y;
            acc.z += v0.z;
            acc.w += v0.w;
        }
        float di = dinv[i];
        float4 y;
        y.x = fmaf(di, acc.x, b4.x);
        y.y = fmaf(di, acc.y, b4.y);
        y.z = fmaf(di, acc.z, b4.z);
        y.w = fmaf(di, acc.w, b4.w);
        *reinterpret_cast<float4*>(out + (size_t)i * F + fq) = y;
        if (STATS) {
            s[0] += y.x; sq[0] = fmaf(y.x, y.x, sq[0]);
            s[1] += y.y; sq[1] = fmaf(y.y, y.y, sq[1]);
            s[2] += y.z; sq[2] = fmaf(y.z, y.z, sq[2]);
            s[3] += y.w; sq[3] = fmaf(y.w, y.w, sq[3]);
        }
    }
    if (STATS) {
        __shared__ float sred[32][8];  // [lane][group]  (F==128 path only)
#pragma unroll
        for (int q = 0; q < 8; ++q) {
            float v = (q < 4) ? s[q] : sq[q - 4];
            sred[lane][grp] = v;
            __syncthreads();
            if (grp == 0) {
                float t = 0.f;
#pragma unroll
                for (int g = 0; g < 8; ++g) t += sred[lane][g];
                int f = fq + (q & 3);
                atomicAdd(stats + ((q < 4) ? f : 128 + f), t);
            }
            __syncthreads();
        }
    }
}

// scale = g * rsqrt(var+eps); shift = be - mean*scale
__global__ void finalize_kernel(const float* __restrict__ stats,
                                const float* __restrict__ g,
                                const float* __restrict__ be, float invn,
                                float* __restrict__ ss) {
    int f = threadIdx.x;
    float mean = stats[f] * invn;
    float var = fmaf(-mean, mean, stats[128 + f] * invn);
    float sc = g[f] * rsqrtf(var + 1e-5f);
    ss[f] = sc;
    ss[128 + f] = fmaf(-mean, sc, be[f]);
}

extern "C" void kernel_launch(void* const* d_in, const int* in_sizes, int n_in,
                              void* d_out, int out_size, void* d_ws,
                              size_t ws_size, hipStream_t stream) {
    const float* x   = (const float*)d_in[0];
    const int*   ei  = (const int*)d_in[1];
    const float* W1  = (const float*)d_in[2];
    const float* b1  = (const float*)d_in[3];
    const float* g1  = (const float*)d_in[4];
    const float* be1 = (const float*)d_in[5];
    const float* W2  = (const float*)d_in[6];
    const float* b2  = (const float*)d_in[7];
    const float* g2  = (const float*)d_in[8];
    const float* be2 = (const float*)d_in[9];
    const float* W3  = (const float*)d_in[10];
    const float* b3  = (const float*)d_in[11];
    float* out = (float*)d_out;

    const int n = in_sizes[0] / 128;
    const int E = in_sizes[1] / 2;
    const int* src = ei;
    const int* dst = ei + E;

    float* wsf    = (float*)d_ws;
    float* dinv   = wsf;                     // n floats
    float* stats  = wsf + n;                 // 256
    float* ss     = stats + 256;             // 256
    int*   rowptr = (int*)(ss + 256);        // n+1 ints
    int*   bsum   = rowptr + (n + 1);        // <=64 ints (scan block sums)
    int*   csrsrc = bsum + 64;               // E ints
    float* bufA   = (float*)(csrsrc + E);    // n*128
    float* bufB   = bufA + (size_t)n * 128;  // n*128

    const int total = n + 1;
    const int nb = (total + 2047) / 2048;    // scan chunks (25 for n=50000)

    // ---- CSR build + dinv ----
    hipMemsetAsync(rowptr, 0, (size_t)total * 4, stream);
    count_deg_kernel<<<(E + 255) / 256, 256, 0, stream>>>(dst, E, rowptr + 1);
    dinv_kernel<<<(n + 255) / 256, 256, 0, stream>>>(rowptr, n, dinv);
    scanA_kernel<<<nb, 256, 0, stream>>>(rowptr, total, bsum);
    scanB_kernel<<<1, 64, 0, stream>>>(bsum, nb);
    scanC_kernel<<<nb, 256, 0, stream>>>(rowptr, total, bsum);
    csr_build_kernel<<<(E + 255) / 256, 256, 0, stream>>>(src, dst, E, rowptr, csrsrc);

    dim3 gemmGrid128((n + 63) / 64, 2);
    dim3 gemmGrid64((n + 63) / 64, 1);

    // aggregate grids: 1024 blocks (stats layers) balances occupancy vs
    // per-feature stat-atomic count; 2048 for the final no-stats layer.
    const int aggGrid128 = 1024;
    const int aggGrid64 = 2048;

    // ---- layer 1 ----
    gemm_k128<128, false><<<gemmGrid128, 256, 0, stream>>>(x, W1, bufA, n, nullptr, dinv);
    hipMemsetAsync(stats, 0, 256 * 4, stream);
    aggregate_kernel<128, true><<<aggGrid128, 256, 0, stream>>>(bufA, csrsrc, rowptr, dinv, b1, bufB, n, stats);
    finalize_kernel<<<1, 128, 0, stream>>>(stats, g1, be1, 1.0f / n, ss);

    // ---- layer 2 ----
    gemm_k128<128, true><<<gemmGrid128, 256, 0, stream>>>(bufB, W2, bufA, n, ss, dinv);
    hipMemsetAsync(stats, 0, 256 * 4, stream);
    aggregate_kernel<128, true><<<aggGrid128, 256, 0, stream>>>(bufA, csrsrc, rowptr, dinv, b2, bufB, n, stats);
    finalize_kernel<<<1, 128, 0, stream>>>(stats, g2, be2, 1.0f / n, ss);

    // ---- layer 3 ----
    gemm_k128<64, true><<<gemmGrid64, 256, 0, stream>>>(bufB, W3, bufA, n, ss, dinv);
    aggregate_kernel<64, false><<<aggGrid64, 256, 0, stream>>>(bufA, csrsrc, rowptr, dinv, b3, out, n, nullptr);
}

// Round 5
// 530.785 us; speedup vs baseline: 1.1005x; 1.1005x over previous
//
#include <hip/hip_runtime.h>
#include <hip/hip_bf16.h>

// 3-layer GCN, CSR gather-reduce, bf16-compressed gather operand.
//   hs = bf16( dinv[row] * (act(prev) @ W) )   (GEMM, act = BN+ReLU fused)
//   y[i] = dinv[i]*(hs[i] + sum_{e: s->i} hs[s]) + b   (fp32 accumulate)
// CSR built per call: count degrees -> 3-phase parallel scan ->
// destructive-cursor placement (rowptr[i] becomes end-of-row i).
// Round-4 lesson: aggregate is L2-miss-path throughput bound; extra
// concurrency (1024 blocks / x4 unroll) regressed. 512 blocks + x2 unroll
// is the measured-best config; this round halves BYTES instead (bf16).

__device__ inline unsigned short f2bf(float f) {  // round-to-nearest-even
    unsigned int u = __float_as_uint(f);
    return (unsigned short)((u + 0x7fff + ((u >> 16) & 1)) >> 16);
}

__global__ void count_deg_kernel(const int* __restrict__ dst, int E,
                                 int* __restrict__ rowptr1 /* rowptr+1 */) {
    int e = blockIdx.x * blockDim.x + threadIdx.x;
    if (e < E) atomicAdd(rowptr1 + dst[e], 1);
}

// dinv[i] = rsqrt(deg_i + 1); deg_i lives at rowptr[i+1] (pre-scan)
__global__ void dinv_kernel(const int* __restrict__ rowptr, int n,
                            float* __restrict__ dinv) {
    int i = blockIdx.x * blockDim.x + threadIdx.x;
    if (i < n) dinv[i] = rsqrtf((float)(rowptr[i + 1] + 1));
}

// ---- 3-phase parallel inclusive scan over rowptr[0..total) ----
__global__ __launch_bounds__(256) void scanA_kernel(int* __restrict__ data,
                                                    int total,
                                                    int* __restrict__ bsum) {
    __shared__ int sh[256];
    const int t = threadIdx.x;
    const int base = blockIdx.x * 2048 + t * 8;
    int v[8];
    int run = 0;
#pragma unroll
    for (int j = 0; j < 8; ++j) {
        int idx = base + j;
        int x = (idx < total) ? data[idx] : 0;
        run += x;
        v[j] = run;
    }
    sh[t] = run;
    __syncthreads();
#pragma unroll
    for (int off = 1; off < 256; off <<= 1) {
        int add = (t >= off) ? sh[t - off] : 0;
        __syncthreads();
        sh[t] += add;
        __syncthreads();
    }
    int prev = (t > 0) ? sh[t - 1] : 0;
#pragma unroll
    for (int j = 0; j < 8; ++j) {
        int idx = base + j;
        if (idx < total) data[idx] = v[j] + prev;
    }
    if (t == 255) bsum[blockIdx.x] = sh[255];
}

__global__ void scanB_kernel(int* __restrict__ bsum, int nb) {
    __shared__ int sh[64];
    const int t = threadIdx.x;
    sh[t] = (t < nb) ? bsum[t] : 0;
    __syncthreads();
#pragma unroll
    for (int off = 1; off < 64; off <<= 1) {
        int add = (t >= off) ? sh[t - off] : 0;
        __syncthreads();
        sh[t] += add;
        __syncthreads();
    }
    if (t < nb) bsum[t] = sh[t];
}

__global__ __launch_bounds__(256) void scanC_kernel(int* __restrict__ data,
                                                    int total,
                                                    const int* __restrict__ bsum) {
    if (blockIdx.x == 0) return;
    const int off = bsum[blockIdx.x - 1];
    const int base = blockIdx.x * 2048 + threadIdx.x * 8;
#pragma unroll
    for (int j = 0; j < 8; ++j) {
        int idx = base + j;
        if (idx < total) data[idx] += off;
    }
}

// destructive cursor: rowptr[d] advances start->end while placing srcs
__global__ void csr_build_kernel(const int* __restrict__ src,
                                 const int* __restrict__ dst, int E,
                                 int* __restrict__ rowptr,
                                 int* __restrict__ csr_src) {
    int e = blockIdx.x * blockDim.x + threadIdx.x;
    if (e < E) {
        int pos = atomicAdd(rowptr + dst[e], 1);
        csr_src[pos] = src[e];
    }
}

// C_bf16[n x NC] = bf16( dinv[row] * (act(A[n x 128]) * W[128 x NC]) )
// act = identity or BN(scale,shift)+ReLU. 64x64 tile, 256 thr, 4x4 micro.
template <int NC, bool TRANS>
__global__ __launch_bounds__(256) void gemm_k128(
    const float* __restrict__ A, const float* __restrict__ W,
    unsigned short* __restrict__ C, int n, const float* __restrict__ ss,
    const float* __restrict__ dinv) {
    __shared__ float As[32][64];  // [k][row]
    __shared__ float Ws[32][64];  // [k][col]
    const int tid = threadIdx.x;
    const int row0 = blockIdx.x * 64;
    const int col0 = blockIdx.y * 64;
    const int tx = tid & 15, ty = tid >> 4;
    const int ar = tid >> 3;        // 0..31
    const int akq = (tid & 7) * 4;  // k quad
    const int wk = tid >> 4;        // 0..15
    const int wjq = (tid & 15) * 4; // col quad
    float acc[4][4] = {};

    for (int kb = 0; kb < 128; kb += 32) {
#pragma unroll
        for (int half = 0; half < 2; ++half) {
            int row = row0 + ar + half * 32;
            float4 v = make_float4(0.f, 0.f, 0.f, 0.f);
            if (row < n)
                v = *reinterpret_cast<const float4*>(A + (size_t)row * 128 + kb + akq);
            if (TRANS) {
                float4 sc = *reinterpret_cast<const float4*>(ss + kb + akq);
                float4 sh = *reinterpret_cast<const float4*>(ss + 128 + kb + akq);
                v.x = fmaxf(fmaf(v.x, sc.x, sh.x), 0.f);
                v.y = fmaxf(fmaf(v.y, sc.y, sh.y), 0.f);
                v.z = fmaxf(fmaf(v.z, sc.z, sh.z), 0.f);
                v.w = fmaxf(fmaf(v.w, sc.w, sh.w), 0.f);
            }
            As[akq + 0][ar + half * 32] = v.x;
            As[akq + 1][ar + half * 32] = v.y;
            As[akq + 2][ar + half * 32] = v.z;
            As[akq + 3][ar + half * 32] = v.w;
        }
#pragma unroll
        for (int half = 0; half < 2; ++half) {
            int k = kb + wk + half * 16;
            float4 w = *reinterpret_cast<const float4*>(W + (size_t)k * NC + col0 + wjq);
            *reinterpret_cast<float4*>(&Ws[wk + half * 16][wjq]) = w;
        }
        __syncthreads();
#pragma unroll
        for (int kk = 0; kk < 32; ++kk) {
            float4 a4 = *reinterpret_cast<const float4*>(&As[kk][ty * 4]);
            float4 b4 = *reinterpret_cast<const float4*>(&Ws[kk][tx * 4]);
            float av[4] = {a4.x, a4.y, a4.z, a4.w};
            float bv[4] = {b4.x, b4.y, b4.z, b4.w};
#pragma unroll
            for (int r = 0; r < 4; ++r)
#pragma unroll
                for (int c = 0; c < 4; ++c)
                    acc[r][c] = fmaf(av[r], bv[c], acc[r][c]);
        }
        __syncthreads();
    }
#pragma unroll
    for (int r = 0; r < 4; ++r) {
        int row = row0 + ty * 4 + r;
        if (row < n) {
            float di = dinv[row];
            unsigned int h0 = f2bf(acc[r][0] * di);
            unsigned int h1 = f2bf(acc[r][1] * di);
            unsigned int h2 = f2bf(acc[r][2] * di);
            unsigned int h3 = f2bf(acc[r][3] * di);
            uint2 o = make_uint2(h0 | (h1 << 16), h2 | (h3 << 16));
            *reinterpret_cast<uint2*>(C + (size_t)row * NC + col0 + tx * 4) = o;
        }
    }
}

// y[i] = dinv[i]*(hs[i] + sum_{e in row i} hs[csr_src[e]]) + bias
// hs is bf16 (packed ushort); fp32 accumulate; one LANES-lane group per
// node, 4 bf16 (8B uint2) per lane, edge loop x2 unrolled. Optional stats.
// rowptr is POST-BUILD (rowptr[i] = end of row i; start = rowptr[i-1]).
template <int F, bool STATS>
__global__ __launch_bounds__(256) void aggregate_kernel(
    const unsigned short* __restrict__ hs, const int* __restrict__ csr_src,
    const int* __restrict__ rowptr, const float* __restrict__ dinv,
    const float* __restrict__ bias, float* __restrict__ out, int n,
    float* __restrict__ stats) {
    const int LANES = F / 4;
    const int GROUPS = 256 / LANES;
    const int lane = threadIdx.x % LANES;
    const int grp = threadIdx.x / LANES;
    const int fq = lane * 4;
    const float4 b4 = *reinterpret_cast<const float4*>(bias + fq);
    float s[4] = {}, sq[4] = {};

    for (int i = blockIdx.x * GROUPS + grp; i < n; i += gridDim.x * GROUPS) {
        int beg = (i == 0) ? 0 : rowptr[i - 1];
        int end = rowptr[i];
        uint2 self = *reinterpret_cast<const uint2*>(hs + (size_t)i * F + fq);
        float a0 = __uint_as_float(self.x << 16);
        float a1 = __uint_as_float(self.x & 0xffff0000u);
        float a2 = __uint_as_float(self.y << 16);
        float a3 = __uint_as_float(self.y & 0xffff0000u);
        int e = beg;
        for (; e + 1 < end; e += 2) {
            int s0 = csr_src[e], s1 = csr_src[e + 1];
            uint2 v0 = *reinterpret_cast<const uint2*>(hs + (size_t)s0 * F + fq);
            uint2 v1 = *reinterpret_cast<const uint2*>(hs + (size_t)s1 * F + fq);
            a0 += __uint_as_float(v0.x << 16) + __uint_as_float(v1.x << 16);
            a1 += __uint_as_float(v0.x & 0xffff0000u) + __uint_as_float(v1.x & 0xffff0000u);
            a2 += __uint_as_float(v0.y << 16) + __uint_as_float(v1.y << 16);
            a3 += __uint_as_float(v0.y & 0xffff0000u) + __uint_as_float(v1.y & 0xffff0000u);
        }
        if (e < end) {
            int s0 = csr_src[e];
            uint2 v0 = *reinterpret_cast<const uint2*>(hs + (size_t)s0 * F + fq);
            a0 += __uint_as_float(v0.x << 16);
            a1 += __uint_as_float(v0.x & 0xffff0000u);
            a2 += __uint_as_float(v0.y << 16);
            a3 += __uint_as_float(v0.y & 0xffff0000u);
        }
        float di = dinv[i];
        float4 y;
        y.x = fmaf(di, a0, b4.x);
        y.y = fmaf(di, a1, b4.y);
        y.z = fmaf(di, a2, b4.z);
        y.w = fmaf(di, a3, b4.w);
        *reinterpret_cast<float4*>(out + (size_t)i * F + fq) = y;
        if (STATS) {
            s[0] += y.x; sq[0] = fmaf(y.x, y.x, sq[0]);
            s[1] += y.y; sq[1] = fmaf(y.y, y.y, sq[1]);
            s[2] += y.z; sq[2] = fmaf(y.z, y.z, sq[2]);
            s[3] += y.w; sq[3] = fmaf(y.w, y.w, sq[3]);
        }
    }
    if (STATS) {
        __shared__ float sred[32][8];  // [lane][group]  (F==128 path only)
#pragma unroll
        for (int q = 0; q < 8; ++q) {
            float v = (q < 4) ? s[q] : sq[q - 4];
            sred[lane][grp] = v;
            __syncthreads();
            if (grp == 0) {
                float t = 0.f;
#pragma unroll
                for (int g = 0; g < 8; ++g) t += sred[lane][g];
                int f = fq + (q & 3);
                atomicAdd(stats + ((q < 4) ? f : 128 + f), t);
            }
            __syncthreads();
        }
    }
}

// scale = g * rsqrt(var+eps); shift = be - mean*scale
__global__ void finalize_kernel(const float* __restrict__ stats,
                                const float* __restrict__ g,
                                const float* __restrict__ be, float invn,
                                float* __restrict__ ss) {
    int f = threadIdx.x;
    float mean = stats[f] * invn;
    float var = fmaf(-mean, mean, stats[128 + f] * invn);
    float sc = g[f] * rsqrtf(var + 1e-5f);
    ss[f] = sc;
    ss[128 + f] = fmaf(-mean, sc, be[f]);
}

extern "C" void kernel_launch(void* const* d_in, const int* in_sizes, int n_in,
                              void* d_out, int out_size, void* d_ws,
                              size_t ws_size, hipStream_t stream) {
    const float* x   = (const float*)d_in[0];
    const int*   ei  = (const int*)d_in[1];
    const float* W1  = (const float*)d_in[2];
    const float* b1  = (const float*)d_in[3];
    const float* g1  = (const float*)d_in[4];
    const float* be1 = (const float*)d_in[5];
    const float* W2  = (const float*)d_in[6];
    const float* b2  = (const float*)d_in[7];
    const float* g2  = (const float*)d_in[8];
    const float* be2 = (const float*)d_in[9];
    const float* W3  = (const float*)d_in[10];
    const float* b3  = (const float*)d_in[11];
    float* out = (float*)d_out;

    const int n = in_sizes[0] / 128;
    const int E = in_sizes[1] / 2;
    const int* src = ei;
    const int* dst = ei + E;

    float* wsf    = (float*)d_ws;
    float* dinv   = wsf;                     // n floats
    float* stats  = wsf + n;                 // 256
    float* ss     = stats + 256;             // 256
    int*   rowptr = (int*)(ss + 256);        // n+1 ints
    int*   bsum   = rowptr + (n + 1);        // <=64 ints (scan block sums)
    int*   csrsrc = bsum + 64;               // E ints
    unsigned short* hsbuf = (unsigned short*)(csrsrc + E);   // n*128 bf16
    float* bufB   = (float*)(hsbuf + (size_t)n * 128);       // n*128 fp32

    const int total = n + 1;
    const int nb = (total + 2047) / 2048;    // scan chunks (25 for n=50000)

    // ---- CSR build + dinv ----
    hipMemsetAsync(rowptr, 0, (size_t)total * 4, stream);
    count_deg_kernel<<<(E + 255) / 256, 256, 0, stream>>>(dst, E, rowptr + 1);
    dinv_kernel<<<(n + 255) / 256, 256, 0, stream>>>(rowptr, n, dinv);
    scanA_kernel<<<nb, 256, 0, stream>>>(rowptr, total, bsum);
    scanB_kernel<<<1, 64, 0, stream>>>(bsum, nb);
    scanC_kernel<<<nb, 256, 0, stream>>>(rowptr, total, bsum);
    csr_build_kernel<<<(E + 255) / 256, 256, 0, stream>>>(src, dst, E, rowptr, csrsrc);

    dim3 gemmGrid128((n + 63) / 64, 2);
    dim3 gemmGrid64((n + 63) / 64, 1);
    const int aggGrid = 512;  // measured-best (round 3); 1024 regressed (round 4)

    // ---- layer 1 ----
    gemm_k128<128, false><<<gemmGrid128, 256, 0, stream>>>(x, W1, hsbuf, n, nullptr, dinv);
    hipMemsetAsync(stats, 0, 256 * 4, stream);
    aggregate_kernel<128, true><<<aggGrid, 256, 0, stream>>>(hsbuf, csrsrc, rowptr, dinv, b1, bufB, n, stats);
    finalize_kernel<<<1, 128, 0, stream>>>(stats, g1, be1, 1.0f / n, ss);

    // ---- layer 2 ----
    gemm_k128<128, true><<<gemmGrid128, 256, 0, stream>>>(bufB, W2, hsbuf, n, ss, dinv);
    hipMemsetAsync(stats, 0, 256 * 4, stream);
    aggregate_kernel<128, true><<<aggGrid, 256, 0, stream>>>(hsbuf, csrsrc, rowptr, dinv, b2, bufB, n, stats);
    finalize_kernel<<<1, 128, 0, stream>>>(stats, g2, be2, 1.0f / n, ss);

    // ---- layer 3 ----
    gemm_k128<64, true><<<gemmGrid64, 256, 0, stream>>>(bufB, W3, hsbuf, n, ss, dinv);
    aggregate_kernel<64, false><<<aggGrid, 256, 0, stream>>>(hsbuf, csrsrc, rowptr, dinv, b3, out, n, nullptr);
}

// Round 6
// 512.188 us; speedup vs baseline: 1.1405x; 1.0363x over previous
//
#include <hip/hip_runtime.h>
#include <hip/hip_bf16.h>

// 3-layer GCN: bf16-MFMA GEMMs + CSR gather-reduce aggregation.
//   hs = bf16( dinv[row] * (act(A) @ W) )     (MFMA GEMM, act = BN+ReLU fused)
//   y[i] = dinv[i]*(hs[i] + sum_{e: s->i} hs[s]) + b  (fp32 acc, bf16 out)
// Lessons encoded:
//  - aggregate is gather-transaction/latency bound (~1.5 TB/s service rate):
//    512 blocks x2 unroll is measured-best (r3); more concurrency (r4) and
//    fewer bytes (r5) don't move it. Left untouched.
//  - fp32 VALU GEMM (~65us each) -> bf16 MFMA (no fp32 MFMA on CDNA4).

typedef __attribute__((ext_vector_type(8))) short short8;   // 8 bf16
typedef __attribute__((ext_vector_type(4))) float f32x4;    // 4 fp32 acc

__device__ inline unsigned short f2bf(float f) {  // round-to-nearest-even
    unsigned int u = __float_as_uint(f);
    return (unsigned short)((u + 0x7fff + ((u >> 16) & 1)) >> 16);
}
__device__ inline float bf2f_lo(unsigned int p) { return __uint_as_float(p << 16); }
__device__ inline float bf2f_hi(unsigned int p) { return __uint_as_float(p & 0xffff0000u); }

__global__ void count_deg_kernel(const int* __restrict__ dst, int E,
                                 int* __restrict__ rowptr1) {
    int e = blockIdx.x * blockDim.x + threadIdx.x;
    if (e < E) atomicAdd(rowptr1 + dst[e], 1);
}

__global__ void dinv_kernel(const int* __restrict__ rowptr, int n,
                            float* __restrict__ dinv) {
    int i = blockIdx.x * blockDim.x + threadIdx.x;
    if (i < n) dinv[i] = rsqrtf((float)(rowptr[i + 1] + 1));
}

// ---- 3-phase parallel inclusive scan over rowptr[0..total) ----
__global__ __launch_bounds__(256) void scanA_kernel(int* __restrict__ data,
                                                    int total,
                                                    int* __restrict__ bsum) {
    __shared__ int sh[256];
    const int t = threadIdx.x;
    const int base = blockIdx.x * 2048 + t * 8;
    int v[8];
    int run = 0;
#pragma unroll
    for (int j = 0; j < 8; ++j) {
        int idx = base + j;
        int x = (idx < total) ? data[idx] : 0;
        run += x;
        v[j] = run;
    }
    sh[t] = run;
    __syncthreads();
#pragma unroll
    for (int off = 1; off < 256; off <<= 1) {
        int add = (t >= off) ? sh[t - off] : 0;
        __syncthreads();
        sh[t] += add;
        __syncthreads();
    }
    int prev = (t > 0) ? sh[t - 1] : 0;
#pragma unroll
    for (int j = 0; j < 8; ++j) {
        int idx = base + j;
        if (idx < total) data[idx] = v[j] + prev;
    }
    if (t == 255) bsum[blockIdx.x] = sh[255];
}

__global__ void scanB_kernel(int* __restrict__ bsum, int nb) {
    __shared__ int sh[64];
    const int t = threadIdx.x;
    sh[t] = (t < nb) ? bsum[t] : 0;
    __syncthreads();
#pragma unroll
    for (int off = 1; off < 64; off <<= 1) {
        int add = (t >= off) ? sh[t - off] : 0;
        __syncthreads();
        sh[t] += add;
        __syncthreads();
    }
    if (t < nb) bsum[t] = sh[t];
}

__global__ __launch_bounds__(256) void scanC_kernel(int* __restrict__ data,
                                                    int total,
                                                    const int* __restrict__ bsum) {
    if (blockIdx.x == 0) return;
    const int off = bsum[blockIdx.x - 1];
    const int base = blockIdx.x * 2048 + threadIdx.x * 8;
#pragma unroll
    for (int j = 0; j < 8; ++j) {
        int idx = base + j;
        if (idx < total) data[idx] += off;
    }
}

__global__ void csr_build_kernel(const int* __restrict__ src,
                                 const int* __restrict__ dst, int E,
                                 int* __restrict__ rowptr,
                                 int* __restrict__ csr_src) {
    int e = blockIdx.x * blockDim.x + threadIdx.x;
    if (e < E) {
        int pos = atomicAdd(rowptr + dst[e], 1);
        csr_src[pos] = src[e];
    }
}

// Wt[nn][k] = bf16(W[k][nn]); K=128 fixed
__global__ void wt_bf16_kernel(const float* __restrict__ W, int NC,
                               unsigned short* __restrict__ Wt) {
    int idx = blockIdx.x * blockDim.x + threadIdx.x;
    if (idx < 128 * NC) {
        int k = idx / NC, nn = idx % NC;
        Wt[nn * 128 + k] = f2bf(W[idx]);
    }
}

// x fp32 -> bf16 (4 elems/thread)
__global__ void xcvt_kernel(const float* __restrict__ x,
                            unsigned short* __restrict__ xb, int total4) {
    int i = blockIdx.x * blockDim.x + threadIdx.x;
    if (i < total4) {
        float4 v = reinterpret_cast<const float4*>(x)[i];
        uint2 p;
        p.x = f2bf(v.x) | ((unsigned)f2bf(v.y) << 16);
        p.y = f2bf(v.z) | ((unsigned)f2bf(v.w) << 16);
        reinterpret_cast<uint2*>(xb)[i] = p;
    }
}

// C[n x NC] = bf16( dinv[row] * (act(A[n x 128]) @ W) ), A bf16, Wt bf16 (NCx128).
// act = identity or BN(scale,shift)+ReLU applied during A-staging.
// Block: 64 rows, 4 waves; wave w -> rows [w*16, w*16+16), all NC cols.
// MFMA 16x16x32 bf16; layouts per m89/m120-verified mappings.
template <int NC, bool BN>
__global__ __launch_bounds__(256) void gemm_mfma(
    const unsigned short* __restrict__ A, const unsigned short* __restrict__ Wt,
    unsigned short* __restrict__ C, int n, const float* __restrict__ ss,
    const float* __restrict__ dinv) {
    __shared__ unsigned short Asd[64][136];   // +8 pad: 2-way bank (free)
    __shared__ unsigned short Bsd[NC][136];
    const int tid = threadIdx.x;
    const int wave = tid >> 6;
    const int lane = tid & 63;
    const int row0 = blockIdx.x * 64;

    // stage Bt (NC x 128)
    for (int idx = tid; idx < NC * 16; idx += 256) {
        int r = idx >> 4;
        int c = (idx & 15) * 8;
        uint4 v = *reinterpret_cast<const uint4*>(Wt + r * 128 + c);
        *reinterpret_cast<uint4*>(&Bsd[r][c]) = v;
    }
    // stage A rows (64 x 128) with optional BN+ReLU
    for (int idx = tid; idx < 64 * 16; idx += 256) {
        int r = idx >> 4;
        int c = (idx & 15) * 8;
        int grow = row0 + r;
        uint4 v = make_uint4(0u, 0u, 0u, 0u);
        if (grow < n)
            v = *reinterpret_cast<const uint4*>(A + (size_t)grow * 128 + c);
        if (BN) {
            unsigned int p[4] = {v.x, v.y, v.z, v.w};
#pragma unroll
            for (int h = 0; h < 4; ++h) {
                int f = c + h * 2;
                float lo = fmaxf(fmaf(bf2f_lo(p[h]), ss[f], ss[128 + f]), 0.f);
                float hi = fmaxf(fmaf(bf2f_hi(p[h]), ss[f + 1], ss[129 + f]), 0.f);
                p[h] = f2bf(lo) | ((unsigned)f2bf(hi) << 16);
            }
            v = make_uint4(p[0], p[1], p[2], p[3]);
        }
        *reinterpret_cast<uint4*>(&Asd[r][c]) = v;
    }
    __syncthreads();

    f32x4 acc[NC / 16];
#pragma unroll
    for (int t = 0; t < NC / 16; ++t) acc[t] = (f32x4)(0.f);

    const int l15 = lane & 15;
    const int quad = lane >> 4;
#pragma unroll
    for (int kb = 0; kb < 128; kb += 32) {
        short8 a = *reinterpret_cast<const short8*>(&Asd[wave * 16 + l15][kb + quad * 8]);
#pragma unroll
        for (int t = 0; t < NC / 16; ++t) {
            short8 b = *reinterpret_cast<const short8*>(&Bsd[t * 16 + l15][kb + quad * 8]);
            acc[t] = __builtin_amdgcn_mfma_f32_16x16x32_bf16(a, b, acc[t], 0, 0, 0);
        }
    }

    // epilogue: row = row0 + wave*16 + quad*4 + r ; col = t*16 + (lane&15)
    const int rbase = row0 + wave * 16 + quad * 4;
    float dv[4] = {0.f, 0.f, 0.f, 0.f};
    if (rbase < n) {  // dinv padded by +64 in ws; values past n guarded below
        float4 d4 = *reinterpret_cast<const float4*>(dinv + rbase);
        dv[0] = d4.x; dv[1] = d4.y; dv[2] = d4.z; dv[3] = d4.w;
    }
#pragma unroll
    for (int t = 0; t < NC / 16; ++t) {
        int col = t * 16 + l15;
#pragma unroll
        for (int r = 0; r < 4; ++r) {
            int row = rbase + r;
            if (row < n)
                C[(size_t)row * NC + col] = f2bf(acc[t][r] * dv[r]);
        }
    }
}

// y[i] = dinv[i]*(hs[i] + sum_{e in row i} hs[csr_src[e]]) + bias
// hs bf16; fp32 accumulate; out bf16 (OBF) or fp32. Optional BN stats.
// rowptr is POST-BUILD (rowptr[i] = end of row i; start = rowptr[i-1]).
template <int F, bool STATS, bool OBF>
__global__ __launch_bounds__(256) void aggregate_kernel(
    const unsigned short* __restrict__ hs, const int* __restrict__ csr_src,
    const int* __restrict__ rowptr, const float* __restrict__ dinv,
    const float* __restrict__ bias, void* __restrict__ outp, int n,
    float* __restrict__ stats) {
    const int LANES = F / 4;
    const int GROUPS = 256 / LANES;
    const int lane = threadIdx.x % LANES;
    const int grp = threadIdx.x / LANES;
    const int fq = lane * 4;
    const float4 b4 = *reinterpret_cast<const float4*>(bias + fq);
    float s[4] = {}, sq[4] = {};

    for (int i = blockIdx.x * GROUPS + grp; i < n; i += gridDim.x * GROUPS) {
        int beg = (i == 0) ? 0 : rowptr[i - 1];
        int end = rowptr[i];
        uint2 self = *reinterpret_cast<const uint2*>(hs + (size_t)i * F + fq);
        float a0 = bf2f_lo(self.x), a1 = bf2f_hi(self.x);
        float a2 = bf2f_lo(self.y), a3 = bf2f_hi(self.y);
        int e = beg;
        for (; e + 1 < end; e += 2) {
            int s0 = csr_src[e], s1 = csr_src[e + 1];
            uint2 v0 = *reinterpret_cast<const uint2*>(hs + (size_t)s0 * F + fq);
            uint2 v1 = *reinterpret_cast<const uint2*>(hs + (size_t)s1 * F + fq);
            a0 += bf2f_lo(v0.x) + bf2f_lo(v1.x);
            a1 += bf2f_hi(v0.x) + bf2f_hi(v1.x);
            a2 += bf2f_lo(v0.y) + bf2f_lo(v1.y);
            a3 += bf2f_hi(v0.y) + bf2f_hi(v1.y);
        }
        if (e < end) {
            int s0 = csr_src[e];
            uint2 v0 = *reinterpret_cast<const uint2*>(hs + (size_t)s0 * F + fq);
            a0 += bf2f_lo(v0.x);
            a1 += bf2f_hi(v0.x);
            a2 += bf2f_lo(v0.y);
            a3 += bf2f_hi(v0.y);
        }
        float di = dinv[i];
        float y0 = fmaf(di, a0, b4.x);
        float y1 = fmaf(di, a1, b4.y);
        float y2 = fmaf(di, a2, b4.z);
        float y3 = fmaf(di, a3, b4.w);
        if (OBF) {
            uint2 pk;
            pk.x = f2bf(y0) | ((unsigned)f2bf(y1) << 16);
            pk.y = f2bf(y2) | ((unsigned)f2bf(y3) << 16);
            *reinterpret_cast<uint2*>((unsigned short*)outp + (size_t)i * F + fq) = pk;
        } else {
            float4 y = make_float4(y0, y1, y2, y3);
            *reinterpret_cast<float4*>((float*)outp + (size_t)i * F + fq) = y;
        }
        if (STATS) {
            s[0] += y0; sq[0] = fmaf(y0, y0, sq[0]);
            s[1] += y1; sq[1] = fmaf(y1, y1, sq[1]);
            s[2] += y2; sq[2] = fmaf(y2, y2, sq[2]);
            s[3] += y3; sq[3] = fmaf(y3, y3, sq[3]);
        }
    }
    if (STATS) {
        __shared__ float sred[32][8];  // [lane][group]  (F==128 path only)
#pragma unroll
        for (int q = 0; q < 8; ++q) {
            float v = (q < 4) ? s[q] : sq[q - 4];
            sred[lane][grp] = v;
            __syncthreads();
            if (grp == 0) {
                float t = 0.f;
#pragma unroll
                for (int g = 0; g < 8; ++g) t += sred[lane][g];
                int f = fq + (q & 3);
                atomicAdd(stats + ((q < 4) ? f : 128 + f), t);
            }
            __syncthreads();
        }
    }
}

// scale = g * rsqrt(var+eps); shift = be - mean*scale
__global__ void finalize_kernel(const float* __restrict__ stats,
                                const float* __restrict__ g,
                                const float* __restrict__ be, float invn,
                                float* __restrict__ ss) {
    int f = threadIdx.x;
    float mean = stats[f] * invn;
    float var = fmaf(-mean, mean, stats[128 + f] * invn);
    float sc = g[f] * rsqrtf(var + 1e-5f);
    ss[f] = sc;
    ss[128 + f] = fmaf(-mean, sc, be[f]);
}

extern "C" void kernel_launch(void* const* d_in, const int* in_sizes, int n_in,
                              void* d_out, int out_size, void* d_ws,
                              size_t ws_size, hipStream_t stream) {
    const float* x   = (const float*)d_in[0];
    const int*   ei  = (const int*)d_in[1];
    const float* W1  = (const float*)d_in[2];
    const float* b1  = (const float*)d_in[3];
    const float* g1  = (const float*)d_in[4];
    const float* be1 = (const float*)d_in[5];
    const float* W2  = (const float*)d_in[6];
    const float* b2  = (const float*)d_in[7];
    const float* g2  = (const float*)d_in[8];
    const float* be2 = (const float*)d_in[9];
    const float* W3  = (const float*)d_in[10];
    const float* b3  = (const float*)d_in[11];
    float* out = (float*)d_out;

    const int n = in_sizes[0] / 128;
    const int E = in_sizes[1] / 2;
    const int* src = ei;
    const int* dst = ei + E;

    float* wsf    = (float*)d_ws;
    float* dinv   = wsf;                         // n + 64 floats (padded)
    float* stats  = dinv + n + 64;               // 256
    float* ss     = stats + 256;                 // 256
    int*   rowptr = (int*)(ss + 256);            // n+1 ints
    int*   bsum   = rowptr + (n + 1);            // 64 ints
    int*   csrsrc = bsum + 64;                   // E ints
    unsigned short* wt1 = (unsigned short*)(csrsrc + E);      // 128*128
    unsigned short* wt2 = wt1 + 128 * 128;                    // 128*128
    unsigned short* wt3 = wt2 + 128 * 128;                    // 64*128
    unsigned short* abuf = wt3 + 64 * 128;                    // n*128 bf16
    unsigned short* hsb  = abuf + (size_t)n * 128;            // n*128 bf16

    const int total = n + 1;
    const int nb = (total + 2047) / 2048;

    // ---- CSR build + dinv + weight/x conversion ----
    hipMemsetAsync(rowptr, 0, (size_t)total * 4, stream);
    count_deg_kernel<<<(E + 255) / 256, 256, 0, stream>>>(dst, E, rowptr + 1);
    dinv_kernel<<<(n + 255) / 256, 256, 0, stream>>>(rowptr, n, dinv);
    scanA_kernel<<<nb, 256, 0, stream>>>(rowptr, total, bsum);
    scanB_kernel<<<1, 64, 0, stream>>>(bsum, nb);
    scanC_kernel<<<nb, 256, 0, stream>>>(rowptr, total, bsum);
    csr_build_kernel<<<(E + 255) / 256, 256, 0, stream>>>(src, dst, E, rowptr, csrsrc);
    wt_bf16_kernel<<<(128 * 128 + 255) / 256, 256, 0, stream>>>(W1, 128, wt1);
    wt_bf16_kernel<<<(128 * 128 + 255) / 256, 256, 0, stream>>>(W2, 128, wt2);
    wt_bf16_kernel<<<(128 * 64 + 255) / 256, 256, 0, stream>>>(W3, 64, wt3);
    xcvt_kernel<<<((n * 32) + 255) / 256, 256, 0, stream>>>(x, abuf, n * 32);

    const int gemmGrid = (n + 63) / 64;
    const int aggGrid = 512;  // measured-best (r3); 1024 regressed (r4)

    // ---- layer 1 ----
    gemm_mfma<128, false><<<gemmGrid, 256, 0, stream>>>(abuf, wt1, hsb, n, nullptr, dinv);
    hipMemsetAsync(stats, 0, 256 * 4, stream);
    aggregate_kernel<128, true, true><<<aggGrid, 256, 0, stream>>>(hsb, csrsrc, rowptr, dinv, b1, abuf, n, stats);
    finalize_kernel<<<1, 128, 0, stream>>>(stats, g1, be1, 1.0f / n, ss);

    // ---- layer 2 ----
    gemm_mfma<128, true><<<gemmGrid, 256, 0, stream>>>(abuf, wt2, hsb, n, ss, dinv);
    hipMemsetAsync(stats, 0, 256 * 4, stream);
    aggregate_kernel<128, true, true><<<aggGrid, 256, 0, stream>>>(hsb, csrsrc, rowptr, dinv, b2, abuf, n, stats);
    finalize_kernel<<<1, 128, 0, stream>>>(stats, g2, be2, 1.0f / n, ss);

    // ---- layer 3 ----
    gemm_mfma<64, true><<<gemmGrid, 256, 0, stream>>>(abuf, wt3, hsb, n, ss, dinv);
    aggregate_kernel<64, false, false><<<aggGrid, 256, 0, stream>>>(hsb, csrsrc, rowptr, dinv, b3, out, n, nullptr);
}